// Round 1
// baseline (350.984 us; speedup 1.0000x reference)
//
#include <hip/hip_runtime.h>
#include <stdint.h>

// Problem dims
#define Bdim 32
#define Ndim 4096
#define Cin  64
#define Cout 64
#define Demb 16

typedef __bf16 bf16x8 __attribute__((ext_vector_type(8)));
typedef float  f32x4  __attribute__((ext_vector_type(4)));

#define GLOBAL_AS(p) ((__attribute__((address_space(1))) void*)(p))
#define LDS_AS(p)    ((__attribute__((address_space(3))) void*)(p))
#define GLL(gp, lp)  __builtin_amdgcn_global_load_lds(GLOBAL_AS(gp), LDS_AS(lp), 16, 0, 0)

__device__ __forceinline__ uint16_t f2bf(float x) {
    union { float f; uint32_t u; } v; v.f = x;
    uint32_t r = v.u + 0x7FFFu + ((v.u >> 16) & 1u);   // RNE, finite inputs
    return (uint16_t)(r >> 16);
}

__device__ __forceinline__ bf16x8 pack8(float4 a, float4 b) {
    union { uint16_t u[8]; bf16x8 v; } r;
    r.u[0] = f2bf(a.x); r.u[1] = f2bf(a.y); r.u[2] = f2bf(a.z); r.u[3] = f2bf(a.w);
    r.u[4] = f2bf(b.x); r.u[5] = f2bf(b.y); r.u[6] = f2bf(b.z); r.u[7] = f2bf(b.w);
    return r.v;
}

// ---------------------------------------------------------------------------
// P1: fused independent prep (blockIdx-partitioned roles, all 256-thread):
//   [0,256)      k1: A~[n][m] = bf16(exp(relu(E[n]·E[m]))) UNNORMALIZED,
//                    invA[n] = 1/rowsum  (normalization folded into k3)
//   [256,2304)   k2: Xtt[b*64+c][m] = bf16(x[b][m][c])  (LDS tile transpose)
//   [2304,6400)  k4a: sd[n] = rsqrt(rowsum(adj[n]) + 0.5); zero scale
//   [6400,6464)  k5a: poolT[d][o*128+ki] = pool[d][ki*64+o]
// ---------------------------------------------------------------------------
__global__ __launch_bounds__(256) void p1_prep(const float* __restrict__ E,
                                               const float* __restrict__ x,
                                               const float* __restrict__ adj,
                                               const float* __restrict__ pool,
                                               uint16_t* __restrict__ A,
                                               float* __restrict__ invA,
                                               uint16_t* __restrict__ Xtt,
                                               float* __restrict__ sd,
                                               float* __restrict__ scale,
                                               float* __restrict__ poolT) {
    __shared__ __align__(16) uint8_t smem[9232];
    const int t = threadIdx.x;
    const int blk = blockIdx.x;

    if (blk < 256) {
        // ---- k1: dynamic adjacency, one pass ----
        float* Er_s = (float*)smem;            // 16x16
        float* red_s = (float*)(smem + 1024);  // 4
        const int n0 = blk * 16;
        Er_s[t] = E[n0 * Demb + t];
        __syncthreads();
        for (int half = 0; half < 2; ++half) {
            float er[8][16];
#pragma unroll
            for (int r = 0; r < 8; ++r)
#pragma unroll
                for (int d = 0; d < 16; ++d) er[r][d] = Er_s[(half * 8 + r) * 16 + d];
            float sacc[8];
#pragma unroll
            for (int r = 0; r < 8; ++r) sacc[r] = 0.f;
            for (int c = 0; c < 16; ++c) {
                const int m = c * 256 + t;
                const float4* ep = (const float4*)(E + (size_t)m * Demb);
                float4 e0 = ep[0], e1 = ep[1], e2 = ep[2], e3 = ep[3];
                float em[16] = {e0.x, e0.y, e0.z, e0.w, e1.x, e1.y, e1.z, e1.w,
                                e2.x, e2.y, e2.z, e2.w, e3.x, e3.y, e3.z, e3.w};
#pragma unroll
                for (int r = 0; r < 8; ++r) {
                    float v = 0.f;
#pragma unroll
                    for (int d = 0; d < 16; ++d) v = fmaf(er[r][d], em[d], v);
                    v = fmaxf(v, 0.f);
                    const float e = __expf(v);
                    sacc[r] += e;
                    A[(size_t)(n0 + half * 8 + r) * Ndim + m] = f2bf(e);
                }
            }
#pragma unroll
            for (int r = 0; r < 8; ++r) {
                float s = sacc[r];
#pragma unroll
                for (int off = 32; off > 0; off >>= 1) s += __shfl_down(s, off, 64);
                __syncthreads();
                if ((t & 63) == 0) red_s[t >> 6] = s;
                __syncthreads();
                if (t == 0)
                    invA[n0 + half * 8 + r] = 1.f / (red_s[0] + red_s[1] + red_s[2] + red_s[3]);
            }
            __syncthreads();
        }
    } else if (blk < 2304) {
        // ---- k2: x transpose to Xtt ----
        auto T = (uint16_t(*)[72])smem;
        const int idx = blk - 256;
        const int m0 = (idx & 63) * 64;
        const int b = idx >> 6;
        const int c = t & 63;
#pragma unroll
        for (int j = 0; j < 16; ++j) {
            const int m = (t >> 6) + j * 4;
            T[c][m] = f2bf(x[((size_t)b * Ndim + (m0 + m)) * Cin + c]);
        }
        __syncthreads();
        const int c2 = t >> 2, mo = (t & 3) * 16;
        const uint4* src = (const uint4*)&T[c2][mo];
        uint4 v0 = src[0], v1 = src[1];
        uint4* dst = (uint4*)(Xtt + (size_t)(b * Cin + c2) * Ndim + m0 + mo);
        dst[0] = v0;
        dst[1] = v1;
    } else if (blk < 6400) {
        // ---- k4a: adj rowsum -> sd; zero scale ----
        float* red_s = (float*)smem;
        const int n = blk - 2304;
        if (n < 16) scale[n * 256 + t] = 0.f;
        const float4* ap = (const float4*)(adj + (size_t)n * Ndim);
        float s = 0.f;
#pragma unroll
        for (int q = 0; q < 4; ++q) {
            float4 a = ap[q * 256 + t];
            s += a.x + a.y + a.z + a.w;
        }
#pragma unroll
        for (int off = 32; off > 0; off >>= 1) s += __shfl_down(s, off, 64);
        if ((t & 63) == 0) red_s[t >> 6] = s;
        __syncthreads();
        if (t == 0) sd[n] = sqrtf(1.f / (red_s[0] + red_s[1] + red_s[2] + red_s[3] + 0.5f));
    } else {
        // ---- k5a: pool transpose ----
        const int idx = blk - 6400;
        const int d = idx >> 2;
        const int base = (idx & 3) * 2048;
#pragma unroll
        for (int j = 0; j < 8; ++j) {
            const int e = base + j * 256 + t;          // e = ki*64 + o
            const float v = pool[d * 8192 + e];
            poolT[d * 8192 + (e & 63) * 128 + (e >> 6)] = v;
        }
    }
}

// ---------------------------------------------------------------------------
// P2: k4b (wave-restructured) + k5b, separate launch so k3 keeps its CUs.
//   [0,256)     k4b: scale[m] += colsum(rowsoftmax(rowsoftmax(sym-norm adj)))
//   [256,1280)  k5b: Wt[n][o*128+ki] = bf16(sum_d E[n,d]*poolT[d][...]); biasn
// ---------------------------------------------------------------------------
__global__ __launch_bounds__(256) void p2_mid(const float* __restrict__ E,
                                              const float* __restrict__ adj,
                                              const float* __restrict__ sd,
                                              const float* __restrict__ poolT,
                                              const float* __restrict__ bias_pool,
                                              float* __restrict__ scale,
                                              uint16_t* __restrict__ Wt,
                                              float* __restrict__ biasn) {
    __shared__ __align__(16) uint8_t smem[16384];
    const int t = threadIdx.x;
    const int blk = blockIdx.x;

    if (blk < 256) {
        // ---- k4b (wave-owned rows) ----
        float* cs = (float*)smem;                     // colsum accumulator [4096]
#pragma unroll
        for (int i = 0; i < 16; ++i) cs[i * 256 + t] = 0.f;
        __syncthreads();

        const int wv = t >> 6, l = t & 63;
        const int nb = blk * 16 + wv * 4;

        float sdm[64];
#pragma unroll
        for (int i = 0; i < 16; ++i) {
            float4 s4 = *(const float4*)(sd + i * 256 + l * 4);
            sdm[i * 4 + 0] = s4.x; sdm[i * 4 + 1] = s4.y;
            sdm[i * 4 + 2] = s4.z; sdm[i * 4 + 3] = s4.w;
        }
        float colsum[64];
#pragma unroll
        for (int k = 0; k < 64; ++k) colsum[k] = 0.f;

        for (int r = 0; r < 4; ++r) {
            const int n = nb + r;
            const float sdn = sd[n];
            float e1[64];
            float s1 = 0.f;
#pragma unroll
            for (int i = 0; i < 16; ++i) {
                float4 a4 = *(const float4*)(adj + (size_t)n * Ndim + i * 256 + l * 4);
                const int c0 = i * 256 + l * 4;
                float vv[4] = {a4.x, a4.y, a4.z, a4.w};
#pragma unroll
                for (int u = 0; u < 4; ++u) {
                    const float vd = vv[u] + ((c0 + u) == n ? 0.5f : 0.f);
                    const float e = __expf(sdn * vd * sdm[i * 4 + u]);
                    e1[i * 4 + u] = e;
                    s1 += e;
                }
            }
#pragma unroll
            for (int off = 32; off > 0; off >>= 1) s1 += __shfl_xor(s1, off, 64);
            const float inv1 = 1.f / s1;
            float s2 = 0.f;
#pragma unroll
            for (int k = 0; k < 64; ++k) {
                const float e = __expf(e1[k] * inv1);
                e1[k] = e;
                s2 += e;
            }
#pragma unroll
            for (int off = 32; off > 0; off >>= 1) s2 += __shfl_xor(s2, off, 64);
            const float inv2 = 1.f / s2;
#pragma unroll
            for (int k = 0; k < 64; ++k) colsum[k] = fmaf(e1[k], inv2, colsum[k]);
        }
        // combine waves in LDS, then one global-atomic pass
#pragma unroll
        for (int k = 0; k < 64; ++k)
            atomicAdd(&cs[(k >> 2) * 256 + l * 4 + (k & 3)], colsum[k]);
        __syncthreads();
#pragma unroll
        for (int i = 0; i < 16; ++i)
            atomicAdd(scale + i * 256 + t, cs[i * 256 + t]);
    } else {
        // ---- k5b ----
        float* En = (float*)smem;   // 32x16
        const int idx = blk - 256;
        const int ec = idx & 7;
        const int n0 = (idx >> 3) * 32;
        En[t] = E[n0 * Demb + t];
        En[t + 256] = E[n0 * Demb + t + 256];
        __syncthreads();

        const int e0 = ec * 1024 + t * 4;
        float4 P[16];
#pragma unroll
        for (int d = 0; d < 16; ++d) P[d] = *(const float4*)(poolT + d * 8192 + e0);

        for (int g = 0; g < 32; ++g) {
            float4 acc = {0.f, 0.f, 0.f, 0.f};
#pragma unroll
            for (int d = 0; d < 16; ++d) {
                const float e = En[g * 16 + d];
                acc.x = fmaf(e, P[d].x, acc.x);
                acc.y = fmaf(e, P[d].y, acc.y);
                acc.z = fmaf(e, P[d].z, acc.z);
                acc.w = fmaf(e, P[d].w, acc.w);
            }
            union { uint16_t u[4]; uint2 v; } r;
            r.u[0] = f2bf(acc.x); r.u[1] = f2bf(acc.y);
            r.u[2] = f2bf(acc.z); r.u[3] = f2bf(acc.w);
            *(uint2*)(Wt + (size_t)(n0 + g) * 8192 + e0) = r.v;
        }

        if (ec == 0) {
            const int o = t & 63, gq = t >> 6;
#pragma unroll
            for (int gi = 0; gi < 8; ++gi) {
                const int g = gi * 4 + gq;
                float a = 0.f;
#pragma unroll
                for (int d = 0; d < 16; ++d) a = fmaf(En[g * 16 + d], bias_pool[d * 64 + o], a);
                biasn[(size_t)(n0 + g) * 64 + o] = a;
            }
        }
    }
}

// ---------------------------------------------------------------------------
// K3 v2: XG[n][j] = invA[n] * sum_m A~[n][m] * Xtt[j][m]  (4096 x 2048 x 4096)
// 8-phase-style pipelined schedule (T3+T4+T2+T5 per the technique catalog):
//   BM=256 x BN=128, BK=64, 512 thr (8 waves, 4Mx2N, 64x64 out/wave)
//   grid 16x16 = 256 blocks = 1/CU; LDS triple-buffered (3 x 48 KiB)
//   stage(kt+2) issued at iteration top into the buffer freed by the
//   end-barrier of kt-1 (race-free); counted s_waitcnt vmcnt(6) once per
//   K-tile (never 0 in steady state) -> 2 K-tiles of loads in flight.
//   Both-sides XOR chunk swizzle (3-bit) on A/B tiles: worst 2-way bank
//   aliasing on ds_read_b128 (free).  Raw s_barrier (NOT __syncthreads —
//   that would drain vmcnt).  s_setprio(1) around each 16-MFMA cluster.
// ---------------------------------------------------------------------------
#define GK 4096
#define GN 2048
#define K3_NT 64
__global__ __launch_bounds__(512) void k3_gemm(const uint16_t* __restrict__ Abf,
                                               const uint16_t* __restrict__ Bbf,
                                               const float* __restrict__ invA,
                                               uint16_t* __restrict__ Cbf) {
    __shared__ __align__(16) uint16_t As[3][256 * 64];   // 3 x 32 KiB
    __shared__ __align__(16) uint16_t Bs[3][128 * 64];   // 3 x 16 KiB
    const int t = threadIdx.x;
    const int lane = t & 63;
    const int wid = t >> 6;
    const int wr = wid >> 1;      // 0..3  (M sub-tile of 64)
    const int wc = wid & 1;       // 0..1  (N sub-tile of 64)

    // XCD-bijective swizzle: 256 blocks, 8 XCDs, 32 contiguous wgids each.
    const int bid = blockIdx.x;
    const int wgid = (bid & 7) * 32 + (bid >> 3);
    const int bm = (wgid >> 4) * 256;   // M tile
    const int bn = (wgid & 15) * 128;   // N tile

    // ---- staging descriptors: thread t owns 16B chunk c = t + i*512 ----
    // chunk c -> row c>>3, chunk-in-row c&7; source col pre-swizzled by
    // (ch ^ (row&7)) so a linear LDS write + swizzled read = bijective pair.
    const uint16_t* asrc[4];
    int adst[4];
#pragma unroll
    for (int i = 0; i < 4; ++i) {
        const int c = t + i * 512;
        const int row = c >> 3, ch = c & 7;
        asrc[i] = Abf + (size_t)(bm + row) * GK + ((ch ^ (row & 7)) << 3);
        adst[i] = c << 3;
    }
    const uint16_t* bsrc[2];
    int bdst[2];
#pragma unroll
    for (int i = 0; i < 2; ++i) {
        const int c = t + i * 512;
        const int row = c >> 3, ch = c & 7;
        bsrc[i] = Bbf + (size_t)(bn + row) * GK + ((ch ^ (row & 7)) << 3);
        bdst[i] = c << 3;
    }

    // ---- fragment read offsets (elements), swizzled to match staging ----
    int offA[4][2], offB[4][2];
#pragma unroll
    for (int f = 0; f < 4; ++f)
#pragma unroll
        for (int ks = 0; ks < 2; ++ks) {
            const int ra = wr * 64 + f * 16 + (lane & 15);
            offA[f][ks] = ra * 64 + (((ks * 4 + (lane >> 4)) ^ (ra & 7)) << 3);
            const int rb = wc * 64 + f * 16 + (lane & 15);
            offB[f][ks] = rb * 64 + (((ks * 4 + (lane >> 4)) ^ (rb & 7)) << 3);
        }

    f32x4 acc[4][4];
#pragma unroll
    for (int i = 0; i < 4; ++i)
#pragma unroll
        for (int j = 0; j < 4; ++j) acc[i][j] = (f32x4){0.f, 0.f, 0.f, 0.f};

#define K3_STAGE(buf, kt)                                  \
    do {                                                   \
        const size_t ko_ = (size_t)(kt) * 64;              \
        GLL(asrc[0] + ko_, &As[buf][adst[0]]);             \
        GLL(asrc[1] + ko_, &As[buf][adst[1]]);             \
        GLL(asrc[2] + ko_, &As[buf][adst[2]]);             \
        GLL(asrc[3] + ko_, &As[buf][adst[3]]);             \
        GLL(bsrc[0] + ko_, &Bs[buf][bdst[0]]);             \
        GLL(bsrc[1] + ko_, &Bs[buf][bdst[1]]);             \
    } while (0)

    // prologue: kt=0 -> buf0, kt=1 -> buf1; wait only for buf0 (6 in flight)
    K3_STAGE(0, 0);
    K3_STAGE(1, 1);
    asm volatile("s_waitcnt vmcnt(6)" ::: "memory");
    __builtin_amdgcn_s_barrier();
    asm volatile("" ::: "memory");

    int cur = 0;
    for (int kt = 0; kt < K3_NT; ++kt) {
        // stage kt+2 into the buffer consumed at kt-1 (freed by end barrier)
        if (kt < K3_NT - 2) {
            int nbuf = cur + 2; if (nbuf >= 3) nbuf -= 3;
            K3_STAGE(nbuf, kt + 2);
        }
        const uint16_t* Ab = As[cur];
        const uint16_t* Bb = Bs[cur];

        // ---- phase 0: ks = 0 (8 ds_read_b128 + 16 MFMA) ----
        bf16x8 a0[4], b0[4];
#pragma unroll
        for (int f = 0; f < 4; ++f) a0[f] = *(const bf16x8*)(Ab + offA[f][0]);
#pragma unroll
        for (int j = 0; j < 4; ++j) b0[j] = *(const bf16x8*)(Bb + offB[j][0]);
        __builtin_amdgcn_s_setprio(1);
#pragma unroll
        for (int f = 0; f < 4; ++f)
#pragma unroll
            for (int j = 0; j < 4; ++j)
                acc[f][j] = __builtin_amdgcn_mfma_f32_16x16x32_bf16(a0[f], b0[j], acc[f][j], 0, 0, 0);
        __builtin_amdgcn_s_setprio(0);
        asm volatile("" ::: "memory");
        __builtin_amdgcn_s_barrier();
        asm volatile("" ::: "memory");

        // ---- phase 1: ks = 1 ----
        bf16x8 a1[4], b1[4];
#pragma unroll
        for (int f = 0; f < 4; ++f) a1[f] = *(const bf16x8*)(Ab + offA[f][1]);
#pragma unroll
        for (int j = 0; j < 4; ++j) b1[j] = *(const bf16x8*)(Bb + offB[j][1]);
        __builtin_amdgcn_s_setprio(1);
#pragma unroll
        for (int f = 0; f < 4; ++f)
#pragma unroll
            for (int j = 0; j < 4; ++j)
                acc[f][j] = __builtin_amdgcn_mfma_f32_16x16x32_bf16(a1[f], b1[j], acc[f][j], 0, 0, 0);
        __builtin_amdgcn_s_setprio(0);

        // release buf[cur]; admit buf[cur+1]: outstanding = 12 -> wait to 6
        if (kt < K3_NT - 2)
            asm volatile("s_waitcnt vmcnt(6)" ::: "memory");
        else
            asm volatile("s_waitcnt vmcnt(0)" ::: "memory");
        __builtin_amdgcn_s_barrier();
        asm volatile("" ::: "memory");

        if (++cur == 3) cur = 0;
    }
#undef K3_STAGE

    // ---- epilogue: fold invA, cast, store ----
#pragma unroll
    for (int f = 0; f < 4; ++f) {
        float invv[4];
#pragma unroll
        for (int r = 0; r < 4; ++r)
            invv[r] = invA[bm + wr * 64 + f * 16 + (lane >> 4) * 4 + r];
#pragma unroll
        for (int j = 0; j < 4; ++j)
#pragma unroll
            for (int r = 0; r < 4; ++r) {
                const int row = bm + wr * 64 + f * 16 + (lane >> 4) * 4 + r;
                const int col = bn + wc * 64 + j * 16 + (lane & 15);
                Cbf[(size_t)row * GN + col] = f2bf(acc[f][j][r] * invv[r]);
            }
    }
}

// ---------------------------------------------------------------------------
// K6 (MFMA, no W staging): one wave per node n.  B-fragments of Wt load
// DIRECTLY from global (each element consumed exactly once).
// LDS = lin_w image only -> one barrier, high occupancy.
// ---------------------------------------------------------------------------
__global__ __launch_bounds__(256) void k6_gconv(const float* __restrict__ x,
                                                const uint16_t* __restrict__ XG,
                                                const uint16_t* __restrict__ Wt,
                                                const float* __restrict__ biasn,
                                                const float* __restrict__ scale,
                                                const float* __restrict__ lin_w,
                                                const float* __restrict__ lin_b,
                                                float* __restrict__ out) {
    __shared__ __align__(16) uint16_t Lws[64][72];
    const int t = threadIdx.x;
    const int n0 = blockIdx.x * 4;

    {
        const int o = t >> 2, i0 = (t & 3) * 16;
        const float4* lp = (const float4*)(lin_w + o * 64 + i0);
        float4 a0 = lp[0], a1 = lp[1], a2 = lp[2], a3 = lp[3];
        union { uint16_t u[16]; uint4 v[2]; } r;
        r.u[0] = f2bf(a0.x); r.u[1] = f2bf(a0.y); r.u[2]  = f2bf(a0.z); r.u[3]  = f2bf(a0.w);
        r.u[4] = f2bf(a1.x); r.u[5] = f2bf(a1.y); r.u[6]  = f2bf(a1.z); r.u[7]  = f2bf(a1.w);
        r.u[8] = f2bf(a2.x); r.u[9] = f2bf(a2.y); r.u[10] = f2bf(a2.z); r.u[11] = f2bf(a2.w);
        r.u[12] = f2bf(a3.x); r.u[13] = f2bf(a3.y); r.u[14] = f2bf(a3.z); r.u[15] = f2bf(a3.w);
        *(uint4*)&Lws[o][i0] = r.v[0];
        *(uint4*)&Lws[o][i0 + 8] = r.v[1];
    }

    const int w = t >> 6, lane = t & 63;
    const int n = n0 + w;
    const int l15 = lane & 15;
    const int q8 = (lane >> 4) * 8;

    bf16x8 a[2][4];
#pragma unroll
    for (int mt = 0; mt < 2; ++mt) {
        const int b = mt * 16 + l15;
        const float* xp = x + ((size_t)b * Ndim + n) * 64 + q8;
        a[mt][0] = pack8(((const float4*)xp)[0], ((const float4*)xp)[1]);
        a[mt][1] = pack8(((const float4*)(xp + 32))[0], ((const float4*)(xp + 32))[1]);
        const uint16_t* gp = XG + (size_t)n * 2048 + b * 64 + q8;
        a[mt][2] = *(const bf16x8*)gp;
        a[mt][3] = *(const bf16x8*)(gp + 32);
    }

    f32x4 accg[2][4], accs[2][4];
#pragma unroll
    for (int mt = 0; mt < 2; ++mt)
#pragma unroll
        for (int j = 0; j < 4; ++j) {
            accg[mt][j] = (f32x4){0.f, 0.f, 0.f, 0.f};
            accs[mt][j] = (f32x4){0.f, 0.f, 0.f, 0.f};
        }

    const uint16_t* wp = Wt + (size_t)n * 8192 + l15 * 128 + q8;

    __syncthreads();   // Lws ready

#pragma unroll
    for (int ks = 0; ks < 4; ++ks) {
        bf16x8 bw[4];
#pragma unroll
        for (int j = 0; j < 4; ++j)
            bw[j] = *(const bf16x8*)(wp + j * 2048 + ks * 32);
#pragma unroll
        for (int mt = 0; mt < 2; ++mt)
#pragma unroll
            for (int j = 0; j < 4; ++j)
                accg[mt][j] = __builtin_amdgcn_mfma_f32_16x16x32_bf16(a[mt][ks], bw[j], accg[mt][j], 0, 0, 0);
        if (ks < 2) {
            bf16x8 bl[4];
#pragma unroll
            for (int j = 0; j < 4; ++j)
                bl[j] = *(const bf16x8*)&Lws[j * 16 + l15][ks * 32 + q8];
#pragma unroll
            for (int mt = 0; mt < 2; ++mt)
#pragma unroll
                for (int j = 0; j < 4; ++j)
                    accs[mt][j] = __builtin_amdgcn_mfma_f32_16x16x32_bf16(a[mt][ks], bl[j], accs[mt][j], 0, 0, 0);
        }
    }

    const float sc = scale[n];
#pragma unroll
    for (int j = 0; j < 4; ++j) {
        const int o = j * 16 + l15;
        const float bn = biasn[(size_t)n * 64 + o];
        const float lb = lin_b[o];
#pragma unroll
        for (int mt = 0; mt < 2; ++mt)
#pragma unroll
            for (int r = 0; r < 4; ++r) {
                const int b = mt * 16 + (lane >> 4) * 4 + r;
                const float gg = accg[mt][j][r] + bn;
                const float xs = sc * accs[mt][j][r] + lb;
                out[((size_t)b * Ndim + n) * 64 + o] = gg + xs / (1.f + __expf(-xs));
            }
    }
}

// ---------------------------------------------------------------------------
extern "C" void kernel_launch(void* const* d_in, const int* in_sizes, int n_in,
                              void* d_out, int out_size, void* d_ws, size_t ws_size,
                              hipStream_t stream) {
    const float* x         = (const float*)d_in[0];
    const float* E         = (const float*)d_in[1];
    const float* pool      = (const float*)d_in[2];
    const float* bias_pool = (const float*)d_in[3];
    const float* lin_w     = (const float*)d_in[4];
    const float* lin_b     = (const float*)d_in[5];
    const float* adj       = (const float*)d_in[6];
    float* out = (float*)d_out;

    uint8_t* ws = (uint8_t*)d_ws;
    uint16_t* A     = (uint16_t*)(ws);                 // 4096*4096*2  = 32 MiB
    uint16_t* Xtt   = (uint16_t*)(ws + 33554432);      // 2048*4096*2  = 16 MiB
    uint16_t* XG    = (uint16_t*)(ws + 50331648);      // 4096*2048*2  = 16 MiB
    uint16_t* Wt    = (uint16_t*)(ws + 67108864);      // 4096*8192*2  = 64 MiB
    float*    biasn = (float*)   (ws + 134217728);     // 4096*64*4    = 1 MiB
    float*    sd    = (float*)   (ws + 135266304);     // 16 KiB
    float*    scale = (float*)   (ws + 135282688);     // 16 KiB
    float*    poolT = (float*)   (ws + 135299072);     // 512 KiB
    float*    invA  = (float*)   (ws + 135823360);     // 16 KiB

    p1_prep<<<dim3(6464), dim3(256), 0, stream>>>(E, x, adj, pool, A, invA, Xtt, sd, scale, poolT);
    p2_mid<<<dim3(1280), dim3(256), 0, stream>>>(E, adj, sd, poolT, bias_pool, scale, Wt, biasn);
    k3_gemm<<<dim3(256), dim3(512), 0, stream>>>(A, Xtt, invA, XG);
    k6_gconv<<<dim3(1024), dim3(256), 0, stream>>>(x, XG, Wt, biasn, scale, lin_w, lin_b, out);
}

// Round 4
// 336.238 us; speedup vs baseline: 1.0439x; 1.0439x over previous
//
#include <hip/hip_runtime.h>
#include <stdint.h>

// Problem dims
#define Bdim 32
#define Ndim 4096
#define Cin  64
#define Cout 64
#define Demb 16

typedef __bf16 bf16x8 __attribute__((ext_vector_type(8)));
typedef float  f32x4  __attribute__((ext_vector_type(4)));

#define GLOBAL_AS(p) ((__attribute__((address_space(1))) void*)(p))
#define LDS_AS(p)    ((__attribute__((address_space(3))) void*)(p))
#define GLL(gp, lp)  __builtin_amdgcn_global_load_lds(GLOBAL_AS(gp), LDS_AS(lp), 16, 0, 0)

__device__ __forceinline__ uint16_t f2bf(float x) {
    union { float f; uint32_t u; } v; v.f = x;
    uint32_t r = v.u + 0x7FFFu + ((v.u >> 16) & 1u);   // RNE, finite inputs
    return (uint16_t)(r >> 16);
}

__device__ __forceinline__ bf16x8 pack8(float4 a, float4 b) {
    union { uint16_t u[8]; bf16x8 v; } r;
    r.u[0] = f2bf(a.x); r.u[1] = f2bf(a.y); r.u[2] = f2bf(a.z); r.u[3] = f2bf(a.w);
    r.u[4] = f2bf(b.x); r.u[5] = f2bf(b.y); r.u[6] = f2bf(b.z); r.u[7] = f2bf(b.w);
    return r.v;
}

// ---------------------------------------------------------------------------
// P1: fused independent prep (blockIdx-partitioned roles, all 256-thread):
//   [0,256)      k1: A~[n][m] = bf16(exp(relu(E[n]·E[m]))) UNNORMALIZED,
//                    invA[n] = 1/rowsum  (normalization folded into k3)
//   [256,2304)   k2: Xtt[b*64+c][m] = bf16(x[b][m][c])  (LDS tile transpose)
//   [2304,6400)  k4a: sd[n] = rsqrt(rowsum(adj[n]) + 0.5); zero scale
//   [6400,6464)  k5a: poolT[d][o*128+ki] = pool[d][ki*64+o]
// ---------------------------------------------------------------------------
__global__ __launch_bounds__(256) void p1_prep(const float* __restrict__ E,
                                               const float* __restrict__ x,
                                               const float* __restrict__ adj,
                                               const float* __restrict__ pool,
                                               uint16_t* __restrict__ A,
                                               float* __restrict__ invA,
                                               uint16_t* __restrict__ Xtt,
                                               float* __restrict__ sd,
                                               float* __restrict__ scale,
                                               float* __restrict__ poolT) {
    __shared__ __align__(16) uint8_t smem[9232];
    const int t = threadIdx.x;
    const int blk = blockIdx.x;

    if (blk < 256) {
        // ---- k1: dynamic adjacency, one pass ----
        float* Er_s = (float*)smem;            // 16x16
        float* red_s = (float*)(smem + 1024);  // 4
        const int n0 = blk * 16;
        Er_s[t] = E[n0 * Demb + t];
        __syncthreads();
        for (int half = 0; half < 2; ++half) {
            float er[8][16];
#pragma unroll
            for (int r = 0; r < 8; ++r)
#pragma unroll
                for (int d = 0; d < 16; ++d) er[r][d] = Er_s[(half * 8 + r) * 16 + d];
            float sacc[8];
#pragma unroll
            for (int r = 0; r < 8; ++r) sacc[r] = 0.f;
            for (int c = 0; c < 16; ++c) {
                const int m = c * 256 + t;
                const float4* ep = (const float4*)(E + (size_t)m * Demb);
                float4 e0 = ep[0], e1 = ep[1], e2 = ep[2], e3 = ep[3];
                float em[16] = {e0.x, e0.y, e0.z, e0.w, e1.x, e1.y, e1.z, e1.w,
                                e2.x, e2.y, e2.z, e2.w, e3.x, e3.y, e3.z, e3.w};
#pragma unroll
                for (int r = 0; r < 8; ++r) {
                    float v = 0.f;
#pragma unroll
                    for (int d = 0; d < 16; ++d) v = fmaf(er[r][d], em[d], v);
                    v = fmaxf(v, 0.f);
                    const float e = __expf(v);
                    sacc[r] += e;
                    A[(size_t)(n0 + half * 8 + r) * Ndim + m] = f2bf(e);
                }
            }
#pragma unroll
            for (int r = 0; r < 8; ++r) {
                float s = sacc[r];
#pragma unroll
                for (int off = 32; off > 0; off >>= 1) s += __shfl_down(s, off, 64);
                __syncthreads();
                if ((t & 63) == 0) red_s[t >> 6] = s;
                __syncthreads();
                if (t == 0)
                    invA[n0 + half * 8 + r] = 1.f / (red_s[0] + red_s[1] + red_s[2] + red_s[3]);
            }
            __syncthreads();
        }
    } else if (blk < 2304) {
        // ---- k2: x transpose to Xtt ----
        auto T = (uint16_t(*)[72])smem;
        const int idx = blk - 256;
        const int m0 = (idx & 63) * 64;
        const int b = idx >> 6;
        const int c = t & 63;
#pragma unroll
        for (int j = 0; j < 16; ++j) {
            const int m = (t >> 6) + j * 4;
            T[c][m] = f2bf(x[((size_t)b * Ndim + (m0 + m)) * Cin + c]);
        }
        __syncthreads();
        const int c2 = t >> 2, mo = (t & 3) * 16;
        const uint4* src = (const uint4*)&T[c2][mo];
        uint4 v0 = src[0], v1 = src[1];
        uint4* dst = (uint4*)(Xtt + (size_t)(b * Cin + c2) * Ndim + m0 + mo);
        dst[0] = v0;
        dst[1] = v1;
    } else if (blk < 6400) {
        // ---- k4a: adj rowsum -> sd; zero scale ----
        float* red_s = (float*)smem;
        const int n = blk - 2304;
        if (n < 16) scale[n * 256 + t] = 0.f;
        const float4* ap = (const float4*)(adj + (size_t)n * Ndim);
        float s = 0.f;
#pragma unroll
        for (int q = 0; q < 4; ++q) {
            float4 a = ap[q * 256 + t];
            s += a.x + a.y + a.z + a.w;
        }
#pragma unroll
        for (int off = 32; off > 0; off >>= 1) s += __shfl_down(s, off, 64);
        if ((t & 63) == 0) red_s[t >> 6] = s;
        __syncthreads();
        if (t == 0) sd[n] = sqrtf(1.f / (red_s[0] + red_s[1] + red_s[2] + red_s[3] + 0.5f));
    } else {
        // ---- k5a: pool transpose ----
        const int idx = blk - 6400;
        const int d = idx >> 2;
        const int base = (idx & 3) * 2048;
#pragma unroll
        for (int j = 0; j < 8; ++j) {
            const int e = base + j * 256 + t;          // e = ki*64 + o
            const float v = pool[d * 8192 + e];
            poolT[d * 8192 + (e & 63) * 128 + (e >> 6)] = v;
        }
    }
}

// ---------------------------------------------------------------------------
// P2: k4b (wave-restructured) + k5b, separate launch so k3 keeps its CUs.
//   [0,256)     k4b: scale[m] += colsum(rowsoftmax(rowsoftmax(sym-norm adj)))
//   [256,1280)  k5b: Wt[n][o*128+ki] = bf16(sum_d E[n,d]*poolT[d][...]); biasn
// ---------------------------------------------------------------------------
__global__ __launch_bounds__(256) void p2_mid(const float* __restrict__ E,
                                              const float* __restrict__ adj,
                                              const float* __restrict__ sd,
                                              const float* __restrict__ poolT,
                                              const float* __restrict__ bias_pool,
                                              float* __restrict__ scale,
                                              uint16_t* __restrict__ Wt,
                                              float* __restrict__ biasn) {
    __shared__ __align__(16) uint8_t smem[16384];
    const int t = threadIdx.x;
    const int blk = blockIdx.x;

    if (blk < 256) {
        // ---- k4b (wave-owned rows) ----
        float* cs = (float*)smem;                     // colsum accumulator [4096]
#pragma unroll
        for (int i = 0; i < 16; ++i) cs[i * 256 + t] = 0.f;
        __syncthreads();

        const int wv = t >> 6, l = t & 63;
        const int nb = blk * 16 + wv * 4;

        float sdm[64];
#pragma unroll
        for (int i = 0; i < 16; ++i) {
            float4 s4 = *(const float4*)(sd + i * 256 + l * 4);
            sdm[i * 4 + 0] = s4.x; sdm[i * 4 + 1] = s4.y;
            sdm[i * 4 + 2] = s4.z; sdm[i * 4 + 3] = s4.w;
        }
        float colsum[64];
#pragma unroll
        for (int k = 0; k < 64; ++k) colsum[k] = 0.f;

        for (int r = 0; r < 4; ++r) {
            const int n = nb + r;
            const float sdn = sd[n];
            float e1[64];
            float s1 = 0.f;
#pragma unroll
            for (int i = 0; i < 16; ++i) {
                float4 a4 = *(const float4*)(adj + (size_t)n * Ndim + i * 256 + l * 4);
                const int c0 = i * 256 + l * 4;
                float vv[4] = {a4.x, a4.y, a4.z, a4.w};
#pragma unroll
                for (int u = 0; u < 4; ++u) {
                    const float vd = vv[u] + ((c0 + u) == n ? 0.5f : 0.f);
                    const float e = __expf(sdn * vd * sdm[i * 4 + u]);
                    e1[i * 4 + u] = e;
                    s1 += e;
                }
            }
#pragma unroll
            for (int off = 32; off > 0; off >>= 1) s1 += __shfl_xor(s1, off, 64);
            const float inv1 = 1.f / s1;
            float s2 = 0.f;
#pragma unroll
            for (int k = 0; k < 64; ++k) {
                const float e = __expf(e1[k] * inv1);
                e1[k] = e;
                s2 += e;
            }
#pragma unroll
            for (int off = 32; off > 0; off >>= 1) s2 += __shfl_xor(s2, off, 64);
            const float inv2 = 1.f / s2;
#pragma unroll
            for (int k = 0; k < 64; ++k) colsum[k] = fmaf(e1[k], inv2, colsum[k]);
        }
        // combine waves in LDS, then one global-atomic pass
#pragma unroll
        for (int k = 0; k < 64; ++k)
            atomicAdd(&cs[(k >> 2) * 256 + l * 4 + (k & 3)], colsum[k]);
        __syncthreads();
#pragma unroll
        for (int i = 0; i < 16; ++i)
            atomicAdd(scale + i * 256 + t, cs[i * 256 + t]);
    } else {
        // ---- k5b ----
        float* En = (float*)smem;   // 32x16
        const int idx = blk - 256;
        const int ec = idx & 7;
        const int n0 = (idx >> 3) * 32;
        En[t] = E[n0 * Demb + t];
        En[t + 256] = E[n0 * Demb + t + 256];
        __syncthreads();

        const int e0 = ec * 1024 + t * 4;
        float4 P[16];
#pragma unroll
        for (int d = 0; d < 16; ++d) P[d] = *(const float4*)(poolT + d * 8192 + e0);

        for (int g = 0; g < 32; ++g) {
            float4 acc = {0.f, 0.f, 0.f, 0.f};
#pragma unroll
            for (int d = 0; d < 16; ++d) {
                const float e = En[g * 16 + d];
                acc.x = fmaf(e, P[d].x, acc.x);
                acc.y = fmaf(e, P[d].y, acc.y);
                acc.z = fmaf(e, P[d].z, acc.z);
                acc.w = fmaf(e, P[d].w, acc.w);
            }
            union { uint16_t u[4]; uint2 v; } r;
            r.u[0] = f2bf(acc.x); r.u[1] = f2bf(acc.y);
            r.u[2] = f2bf(acc.z); r.u[3] = f2bf(acc.w);
            *(uint2*)(Wt + (size_t)(n0 + g) * 8192 + e0) = r.v;
        }

        if (ec == 0) {
            const int o = t & 63, gq = t >> 6;
#pragma unroll
            for (int gi = 0; gi < 8; ++gi) {
                const int g = gi * 4 + gq;
                float a = 0.f;
#pragma unroll
                for (int d = 0; d < 16; ++d) a = fmaf(En[g * 16 + d], bias_pool[d * 64 + o], a);
                biasn[(size_t)(n0 + g) * 64 + o] = a;
            }
        }
    }
}

// ---------------------------------------------------------------------------
// K3 v5: XG[n][j] = invA[n] * sum_m A~[n][m] * Xtt[j][m]  (4096 x 2048 x 4096)
// SAFE double-buffered 2-phase (catalog T3-minimum), after v3/v4's novel
// 3-buffer counted-vmcnt schedule failed deterministically twice:
//   - 128x128 tile, BK=64, 256 thr (4 waves, 2Mx2N, 64x64 out/wave)
//   - LDS 2 x 32 KiB (dbuf) -> 2 blocks/CU (inter-block barrier overlap)
//   - per tile: STAGE(buf^1, kt+1) 8 GLLs; read 16 frags + 32 MFMA on buf;
//     ONE __syncthreads per BK=64 (vs R0's two per BK=32: 4x fewer drains);
//     staging latency covered by the 32 MFMAs before the drain.
//   - all sync via __syncthreads (full vmcnt+lgkm drain semantics — no raw
//     barriers, no hand-counted vmcnt; hazards provably covered)
//   - XOR chunk swizzle (R0/R1-proven addressing), XCD-bijective block
//     swizzle (512 blocks % 8 == 0), invA folded into epilogue (R0-proven).
// ---------------------------------------------------------------------------
#define GK 4096
#define GN 2048
#define K3_NT 64
__global__ __launch_bounds__(256) void k3_gemm(const uint16_t* __restrict__ Abf,
                                               const uint16_t* __restrict__ Bbf,
                                               const float* __restrict__ invA,
                                               uint16_t* __restrict__ Cbf) {
    __shared__ __align__(16) uint16_t As[2][128 * 64];   // 2 x 16 KiB
    __shared__ __align__(16) uint16_t Bs[2][128 * 64];   // 2 x 16 KiB
    const int t = threadIdx.x;
    const int lane = t & 63;
    const int wid = t >> 6;
    const int wr = wid >> 1;      // 0..1 (M sub-tile of 64)
    const int wc = wid & 1;       // 0..1 (N sub-tile of 64)

    // XCD-bijective swizzle: 512 blocks, 8 XCDs, 64 contiguous wgids each.
    const int bid = blockIdx.x;
    const int wgid = (bid & 7) * 64 + (bid >> 3);
    const int bm = (wgid >> 4) * 128;   // 32 M tiles
    const int bn = (wgid & 15) * 128;   // 16 N tiles

    // ---- staging: thread t owns 16B chunk c = t + i*256 (c in [0,1024)) ----
    // chunk c -> row c>>3, chunk-in-row c&7; source col pre-swizzled by
    // (ch ^ (row&7)) so linear LDS write + swizzled read = bijective pair.
    const uint16_t* asrc[4];
    const uint16_t* bsrc[4];
    int cdst[4];
#pragma unroll
    for (int i = 0; i < 4; ++i) {
        const int c = t + i * 256;
        const int row = c >> 3, ch = c & 7;
        asrc[i] = Abf + (size_t)(bm + row) * GK + ((ch ^ (row & 7)) << 3);
        bsrc[i] = Bbf + (size_t)(bn + row) * GK + ((ch ^ (row & 7)) << 3);
        cdst[i] = c << 3;
    }

    // ---- fragment read offsets (elements), swizzled to match staging ----
    int offA[4][2], offB[4][2];
#pragma unroll
    for (int f = 0; f < 4; ++f)
#pragma unroll
        for (int ks = 0; ks < 2; ++ks) {
            const int ra = wr * 64 + f * 16 + (lane & 15);
            offA[f][ks] = ra * 64 + (((ks * 4 + (lane >> 4)) ^ (ra & 7)) << 3);
            const int rb = wc * 64 + f * 16 + (lane & 15);
            offB[f][ks] = rb * 64 + (((ks * 4 + (lane >> 4)) ^ (rb & 7)) << 3);
        }

    f32x4 acc[4][4];
#pragma unroll
    for (int i = 0; i < 4; ++i)
#pragma unroll
        for (int j = 0; j < 4; ++j) acc[i][j] = (f32x4){0.f, 0.f, 0.f, 0.f};

#define K3_STAGE(buf, kt)                                  \
    do {                                                   \
        const size_t ko_ = (size_t)(kt) * 64;              \
        GLL(asrc[0] + ko_, &As[buf][cdst[0]]);             \
        GLL(asrc[1] + ko_, &As[buf][cdst[1]]);             \
        GLL(asrc[2] + ko_, &As[buf][cdst[2]]);             \
        GLL(asrc[3] + ko_, &As[buf][cdst[3]]);             \
        GLL(bsrc[0] + ko_, &Bs[buf][cdst[0]]);             \
        GLL(bsrc[1] + ko_, &Bs[buf][cdst[1]]);             \
        GLL(bsrc[2] + ko_, &Bs[buf][cdst[2]]);             \
        GLL(bsrc[3] + ko_, &Bs[buf][cdst[3]]);             \
    } while (0)

    // prologue: tile 0 -> buf 0; full drain via __syncthreads
    K3_STAGE(0, 0);
    __syncthreads();

    for (int kt = 0; kt < K3_NT; ++kt) {
        const int cur = kt & 1;
        // issue next tile's 8 GLLs into the other buffer (write-after-read
        // hazard vs last iter's reads of buf^1: closed by previous barrier)
        if (kt < K3_NT - 1) K3_STAGE(cur ^ 1, kt + 1);

        const uint16_t* Ab = As[cur];
        const uint16_t* Bb = Bs[cur];
        bf16x8 af[4][2], bfr[4][2];
#pragma unroll
        for (int ks = 0; ks < 2; ++ks) {
#pragma unroll
            for (int f = 0; f < 4; ++f) af[f][ks] = *(const bf16x8*)(Ab + offA[f][ks]);
#pragma unroll
            for (int j = 0; j < 4; ++j) bfr[j][ks] = *(const bf16x8*)(Bb + offB[j][ks]);
        }
        __builtin_amdgcn_s_setprio(1);
#pragma unroll
        for (int ks = 0; ks < 2; ++ks)
#pragma unroll
            for (int f = 0; f < 4; ++f)
#pragma unroll
                for (int j = 0; j < 4; ++j)
                    acc[f][j] = __builtin_amdgcn_mfma_f32_16x16x32_bf16(af[f][ks], bfr[j][ks], acc[f][j], 0, 0, 0);
        __builtin_amdgcn_s_setprio(0);
        // single full-drain barrier per BK=64 tile: retires this iter's 8
        // GLLs (next tile) + all LDS reads; staging latency was covered by
        // the 32 MFMAs above.
        __syncthreads();
    }
#undef K3_STAGE

    // ---- epilogue: fold invA, cast, store ----
#pragma unroll
    for (int f = 0; f < 4; ++f) {
        float invv[4];
#pragma unroll
        for (int r = 0; r < 4; ++r)
            invv[r] = invA[bm + wr * 64 + f * 16 + (lane >> 4) * 4 + r];
#pragma unroll
        for (int j = 0; j < 4; ++j)
#pragma unroll
            for (int r = 0; r < 4; ++r) {
                const int row = bm + wr * 64 + f * 16 + (lane >> 4) * 4 + r;
                const int col = bn + wc * 64 + j * 16 + (lane & 15);
                Cbf[(size_t)row * GN + col] = f2bf(acc[f][j][r] * invv[r]);
            }
    }
}

// ---------------------------------------------------------------------------
// K6 (MFMA, no W staging): one wave per node n.  B-fragments of Wt load
// DIRECTLY from global (each element consumed exactly once).
// LDS = lin_w image only -> one barrier, high occupancy.
// ---------------------------------------------------------------------------
__global__ __launch_bounds__(256) void k6_gconv(const float* __restrict__ x,
                                                const uint16_t* __restrict__ XG,
                                                const uint16_t* __restrict__ Wt,
                                                const float* __restrict__ biasn,
                                                const float* __restrict__ scale,
                                                const float* __restrict__ lin_w,
                                                const float* __restrict__ lin_b,
                                                float* __restrict__ out) {
    __shared__ __align__(16) uint16_t Lws[64][72];
    const int t = threadIdx.x;
    const int n0 = blockIdx.x * 4;

    {
        const int o = t >> 2, i0 = (t & 3) * 16;
        const float4* lp = (const float4*)(lin_w + o * 64 + i0);
        float4 a0 = lp[0], a1 = lp[1], a2 = lp[2], a3 = lp[3];
        union { uint16_t u[16]; uint4 v[2]; } r;
        r.u[0] = f2bf(a0.x); r.u[1] = f2bf(a0.y); r.u[2]  = f2bf(a0.z); r.u[3]  = f2bf(a0.w);
        r.u[4] = f2bf(a1.x); r.u[5] = f2bf(a1.y); r.u[6]  = f2bf(a1.z); r.u[7]  = f2bf(a1.w);
        r.u[8] = f2bf(a2.x); r.u[9] = f2bf(a2.y); r.u[10] = f2bf(a2.z); r.u[11] = f2bf(a2.w);
        r.u[12] = f2bf(a3.x); r.u[13] = f2bf(a3.y); r.u[14] = f2bf(a3.z); r.u[15] = f2bf(a3.w);
        *(uint4*)&Lws[o][i0] = r.v[0];
        *(uint4*)&Lws[o][i0 + 8] = r.v[1];
    }

    const int w = t >> 6, lane = t & 63;
    const int n = n0 + w;
    const int l15 = lane & 15;
    const int q8 = (lane >> 4) * 8;

    bf16x8 a[2][4];
#pragma unroll
    for (int mt = 0; mt < 2; ++mt) {
        const int b = mt * 16 + l15;
        const float* xp = x + ((size_t)b * Ndim + n) * 64 + q8;
        a[mt][0] = pack8(((const float4*)xp)[0], ((const float4*)xp)[1]);
        a[mt][1] = pack8(((const float4*)(xp + 32))[0], ((const float4*)(xp + 32))[1]);
        const uint16_t* gp = XG + (size_t)n * 2048 + b * 64 + q8;
        a[mt][2] = *(const bf16x8*)gp;
        a[mt][3] = *(const bf16x8*)(gp + 32);
    }

    f32x4 accg[2][4], accs[2][4];
#pragma unroll
    for (int mt = 0; mt < 2; ++mt)
#pragma unroll
        for (int j = 0; j < 4; ++j) {
            accg[mt][j] = (f32x4){0.f, 0.f, 0.f, 0.f};
            accs[mt][j] = (f32x4){0.f, 0.f, 0.f, 0.f};
        }

    const uint16_t* wp = Wt + (size_t)n * 8192 + l15 * 128 + q8;

    __syncthreads();   // Lws ready

#pragma unroll
    for (int ks = 0; ks < 4; ++ks) {
        bf16x8 bw[4];
#pragma unroll
        for (int j = 0; j < 4; ++j)
            bw[j] = *(const bf16x8*)(wp + j * 2048 + ks * 32);
#pragma unroll
        for (int mt = 0; mt < 2; ++mt)
#pragma unroll
            for (int j = 0; j < 4; ++j)
                accg[mt][j] = __builtin_amdgcn_mfma_f32_16x16x32_bf16(a[mt][ks], bw[j], accg[mt][j], 0, 0, 0);
        if (ks < 2) {
            bf16x8 bl[4];
#pragma unroll
            for (int j = 0; j < 4; ++j)
                bl[j] = *(const bf16x8*)&Lws[j * 16 + l15][ks * 32 + q8];
#pragma unroll
            for (int mt = 0; mt < 2; ++mt)
#pragma unroll
                for (int j = 0; j < 4; ++j)
                    accs[mt][j] = __builtin_amdgcn_mfma_f32_16x16x32_bf16(a[mt][ks], bl[j], accs[mt][j], 0, 0, 0);
        }
    }

    const float sc = scale[n];
#pragma unroll
    for (int j = 0; j < 4; ++j) {
        const int o = j * 16 + l15;
        const float bn = biasn[(size_t)n * 64 + o];
        const float lb = lin_b[o];
#pragma unroll
        for (int mt = 0; mt < 2; ++mt)
#pragma unroll
            for (int r = 0; r < 4; ++r) {
                const int b = mt * 16 + (lane >> 4) * 4 + r;
                const float gg = accg[mt][j][r] + bn;
                const float xs = sc * accs[mt][j][r] + lb;
                out[((size_t)b * Ndim + n) * 64 + o] = gg + xs / (1.f + __expf(-xs));
            }
    }
}

// ---------------------------------------------------------------------------
extern "C" void kernel_launch(void* const* d_in, const int* in_sizes, int n_in,
                              void* d_out, int out_size, void* d_ws, size_t ws_size,
                              hipStream_t stream) {
    const float* x         = (const float*)d_in[0];
    const float* E         = (const float*)d_in[1];
    const float* pool      = (const float*)d_in[2];
    const float* bias_pool = (const float*)d_in[3];
    const float* lin_w     = (const float*)d_in[4];
    const float* lin_b     = (const float*)d_in[5];
    const float* adj       = (const float*)d_in[6];
    float* out = (float*)d_out;

    uint8_t* ws = (uint8_t*)d_ws;
    uint16_t* A     = (uint16_t*)(ws);                 // 4096*4096*2  = 32 MiB
    uint16_t* Xtt   = (uint16_t*)(ws + 33554432);      // 2048*4096*2  = 16 MiB
    uint16_t* XG    = (uint16_t*)(ws + 50331648);      // 4096*2048*2  = 16 MiB
    uint16_t* Wt    = (uint16_t*)(ws + 67108864);      // 4096*8192*2  = 64 MiB
    float*    biasn = (float*)   (ws + 134217728);     // 4096*64*4    = 1 MiB
    float*    sd    = (float*)   (ws + 135266304);     // 16 KiB
    float*    scale = (float*)   (ws + 135282688);     // 16 KiB
    float*    poolT = (float*)   (ws + 135299072);     // 512 KiB
    float*    invA  = (float*)   (ws + 135823360);     // 16 KiB

    p1_prep<<<dim3(6464), dim3(256), 0, stream>>>(E, x, adj, pool, A, invA, Xtt, sd, scale, poolT);
    p2_mid<<<dim3(1280), dim3(256), 0, stream>>>(E, adj, sd, poolT, bias_pool, scale, Wt, biasn);
    k3_gemm<<<dim3(512), dim3(256), 0, stream>>>(A, Xtt, invA, XG);
    k6_gconv<<<dim3(1024), dim3(256), 0, stream>>>(x, XG, Wt, biasn, scale, lin_w, lin_b, out);
}